// Round 8
// baseline (15.078 us; speedup 1.0000x reference)
//
#include <hip/hip_runtime.h>

// PrRoIPool forward. features [2,64,100,100] f32, rois [256,5], out [256,64,7,7].
//
// Separable analytic integral of bilinear interp over each bin. x: fixed 8-px
// window (2x float4, unaligned ok), start clamped in-image; out-of-support
// weights exactly zero. y: dynamic union of two vertically-adjacent bins'
// supports (p-pair per thread, r7), processed in ROW PAIRS (round-8 change).
//
// Model through r7: ~5us dispatch + ~3.5us data-return + ~2.5us VALU issue +
// ~2.5-3us EXPOSED LOAD LATENCY (r7's byte win was offset by TLP drop 12->7
// waves/SIMD with a depth-1-prefetch serial loop). Round-8 attacks latency
// only (bytes/threads unchanged): (a) first row-pair loads issued BEFORE the
// 72-instr wx computation; (b) pair-wise loop keeps 4 row-loads in flight
// with ~120cy of compute per iteration; (c) phantom odd row = address clamped
// to he + analytically-zero weight (both cdf args <= -1) -> no tail peel,
// no divergence.

constexpr int OUT_H = 7, OUT_W = 7;
constexpr float SPATIAL_SCALE = 0.25f;
constexpr int CH = 64, FH = 100, FW = 100;
constexpr int SUPX = 8;
constexpr int N_XCD = 8;

typedef float f4u __attribute__((ext_vector_type(4), aligned(4)));

__device__ __forceinline__ float hat_cdf_c(float t) {
    // cdf(t) - 0.5 (constant cancels in differences): s=clamp(t,-1,1),
    // s*(1-|s|/2).  min(max()) -> v_med3_f32; |s| is a free input modifier.
    float s = fminf(fmaxf(t, -1.0f), 1.0f);
    return s * fmaf(-0.5f, fabsf(s), 1.0f);
}

__device__ __forceinline__ float row_dot(const float wx[SUPX], f4u a, f4u b) {
    float rsA = fmaf(wx[0], a.x,
                fmaf(wx[1], a.y,
                fmaf(wx[2], a.z, wx[3] * a.w)));
    float rsB = fmaf(wx[4], b.x,
                fmaf(wx[5], b.y,
                fmaf(wx[6], b.z, wx[7] * b.w)));
    return rsA + rsB;
}

__global__ __launch_bounds__(256) void prroi_pool_kernel(
    const float* __restrict__ feat, const float* __restrict__ rois,
    float* __restrict__ out, int n_rois) {
    // Bijective XCD swizzle (nwg = 1792 = 8*224) + c-major decode: XCD k
    // touches only channels [8k, 8k+8) -> per-XCD working set L2-resident.
    int nwg = gridDim.x;
    int cpx = nwg / N_XCD;
    int chunk = (blockIdx.x % N_XCD) * cpx + blockIdx.x / N_XCD;
    int t = chunk * 256 + threadIdx.x;
    int total = n_rois * CH * 4 * OUT_W;
    if (t >= total) return;

    // item = ((c*n_rois + n)*4 + k)*7 + q ; thread covers p0=2k (and p1=2k+1)
    int q = t % OUT_W;
    int rest = t / OUT_W;
    int k = rest & 3;
    rest >>= 2;
    int n = rest % n_rois;
    int c = rest / n_rois;
    int p0 = 2 * k;
    int dp = (k < 3) ? 1 : 0;  // k=3 -> single bin p=6

    const float* r = rois + n * 5;
    int b = (int)r[0];
    float x1 = r[1] * SPATIAL_SCALE;
    float y1 = r[2] * SPATIAL_SCALE;
    float x2 = r[3] * SPATIAL_SCALE;
    float y2 = r[4] * SPATIAL_SCALE;
    float bw = fmaxf(x2 - x1, 0.0f) * (1.0f / OUT_W);
    float bh = fmaxf(y2 - y1, 0.0f) * (1.0f / OUT_H);

    float u0x = x1 + (float)q * bw, u1x = u0x + bw;
    float u0yA = y1 + (float)p0 * bh;             // bin A = [u0yA, u0yA+bh]
    float u1yB = y1 + (float)(p0 + dp + 1) * bh;  // bottom of bin B

    int ws = min(max((int)ceilf(u0x - 1.0f), 0), FW - SUPX);
    int hs = max((int)ceilf(u0yA - 1.0f), 0);
    int he = min((int)floorf(u1yB + 1.0f), FH - 1);
    if (he < hs) he = hs;
    int rows = he - hs + 1;       // 1..14
    int pairs = (rows + 1) >> 1;  // 1..7

    const float* base = feat + (((size_t)b * CH + c) * FH) * FW + ws;
    const float* rp = base + hs * FW;
    const float* rend = base + he * FW;

    // Issue the first row-pair loads BEFORE the wx computation so their
    // latency hides under ~150cy of weight VALU.
    const float* rp1 = rp + FW; rp1 = (rp1 > rend) ? rend : rp1;
    f4u a0 = *reinterpret_cast<const f4u*>(rp);
    f4u b0 = *reinterpret_cast<const f4u*>(rp + 4);
    f4u a1 = *reinterpret_cast<const f4u*>(rp1);
    f4u b1 = *reinterpret_cast<const f4u*>(rp1 + 4);

    float wx[SUPX];
    float dx0 = u0x - (float)ws, dx1 = u1x - (float)ws;
#pragma unroll
    for (int j = 0; j < SUPX; ++j) {
        wx[j] = hat_cdf_c(dx1) - hat_cdf_c(dx0);
        dx0 -= 1.0f; dx1 -= 1.0f;
    }

    // Incremental wy arguments for both bins (decrement 1 per row).
    float dA0 = u0yA - (float)hs, dA1 = dA0 + bh;
    float dB0 = dA0 + (float)dp * bh, dB1 = dB0 + bh;
    float accA = 0.0f, accB = 0.0f;

    for (int ip = 0; ip < pairs - 1; ++ip) {
        // Prefetch next pair. rn0 (even row) is provably in-range for
        // ip < pairs-1; rn1 may be phantom only in the final pair.
        const float* rn0 = rp + 2 * FW;
        const float* rn1 = rn0 + FW; rn1 = (rn1 > rend) ? rend : rn1;
        f4u na0 = *reinterpret_cast<const f4u*>(rn0);
        f4u nb0 = *reinterpret_cast<const f4u*>(rn0 + 4);
        f4u na1 = *reinterpret_cast<const f4u*>(rn1);
        f4u nb1 = *reinterpret_cast<const f4u*>(rn1 + 4);

        float wyA = hat_cdf_c(dA1) - hat_cdf_c(dA0);
        float wyB = hat_cdf_c(dB1) - hat_cdf_c(dB0);
        dA0 -= 1.0f; dA1 -= 1.0f; dB0 -= 1.0f; dB1 -= 1.0f;
        float rs = row_dot(wx, a0, b0);
        accA = fmaf(wyA, rs, accA);
        accB = fmaf(wyB, rs, accB);

        wyA = hat_cdf_c(dA1) - hat_cdf_c(dA0);
        wyB = hat_cdf_c(dB1) - hat_cdf_c(dB0);
        dA0 -= 1.0f; dA1 -= 1.0f; dB0 -= 1.0f; dB1 -= 1.0f;
        rs = row_dot(wx, a1, b1);
        accA = fmaf(wyA, rs, accA);
        accB = fmaf(wyB, rs, accB);

        a0 = na0; b0 = nb0; a1 = na1; b1 = nb1;
        rp = rn0;
    }
    // Final pair; odd-rows case makes row 2*pairs-1 phantom: its address was
    // clamped to he and its analytic weight is exactly zero.
    {
        float wyA = hat_cdf_c(dA1) - hat_cdf_c(dA0);
        float wyB = hat_cdf_c(dB1) - hat_cdf_c(dB0);
        dA0 -= 1.0f; dA1 -= 1.0f; dB0 -= 1.0f; dB1 -= 1.0f;
        float rs = row_dot(wx, a0, b0);
        accA = fmaf(wyA, rs, accA);
        accB = fmaf(wyB, rs, accB);

        wyA = hat_cdf_c(dA1) - hat_cdf_c(dA0);
        wyB = hat_cdf_c(dB1) - hat_cdf_c(dB0);
        rs = row_dot(wx, a1, b1);
        accA = fmaf(wyA, rs, accA);
        accB = fmaf(wyB, rs, accB);
    }

    float area = bw * bh;
    float inv = 1.0f / fmaxf(area, 1e-12f);
    bool ok = area > 0.0f;
    size_t obase = ((size_t)n * CH + c) * (OUT_H * OUT_W) + q;
    out[obase + (size_t)p0 * OUT_W] = ok ? accA * inv : 0.0f;
    if (dp) out[obase + (size_t)(p0 + 1) * OUT_W] = ok ? accB * inv : 0.0f;
}

extern "C" void kernel_launch(void* const* d_in, const int* in_sizes, int n_in,
                              void* d_out, int out_size, void* d_ws, size_t ws_size,
                              hipStream_t stream) {
    const float* feat = (const float*)d_in[0];
    const float* rois = (const float*)d_in[1];
    float* out = (float*)d_out;
    int n_rois = in_sizes[1] / 5;
    int total = n_rois * CH * 4 * OUT_W;      // 458752
    int blocks = (total + 255) / 256;         // 1792 = 8 * 224
    hipLaunchKernelGGL(prroi_pool_kernel, dim3(blocks), dim3(256), 0, stream,
                       feat, rois, out, n_rois);
}

// Round 9
// 13.412 us; speedup vs baseline: 1.1242x; 1.1242x over previous
//
#include <hip/hip_runtime.h>

// PrRoIPool forward. features [2,64,100,100] f32, rois [256,5], out [256,64,7,7].
//
// Separable analytic integral of bilinear interp over each bin. x: fixed 8-px
// window (2x float4, unaligned ok), start clamped in-image; out-of-support
// weights exactly zero. y: dynamic union of two vertically-adjacent bins'
// supports, one thread per (c,n,p-pair,q), depth-1 pipelined row loop (= r7,
// best measured 13.47us).
//
// Round-9 (VALU-issue cuts only; bytes/threads/mapping untouched):
//  - NR=256 templated decode: & / >> instead of runtime div/mod (~25 instr)
//  - shared-mid y weights: adjacent bins share edge u1A==u0B, so 3 cdf evals
//    per row instead of 4 (dp=0 -> wyB==0, accB never stored)
//  - row-0 loads issued above the 72-instr wx computation (free reorder)

constexpr int OUT_H = 7, OUT_W = 7;
constexpr float SPATIAL_SCALE = 0.25f;
constexpr int CH = 64, FH = 100, FW = 100;
constexpr int SUPX = 8;
constexpr int N_XCD = 8;

typedef float f4u __attribute__((ext_vector_type(4), aligned(4)));

__device__ __forceinline__ float hat_cdf_c(float t) {
    // cdf(t) - 0.5 (constant cancels in differences): s=clamp(t,-1,1),
    // s*(1-|s|/2).  min(max()) -> v_med3_f32; |s| is a free input modifier.
    float s = fminf(fmaxf(t, -1.0f), 1.0f);
    return s * fmaf(-0.5f, fabsf(s), 1.0f);
}

__device__ __forceinline__ float row_dot(const float wx[SUPX], f4u a, f4u b) {
    float rsA = fmaf(wx[0], a.x,
                fmaf(wx[1], a.y,
                fmaf(wx[2], a.z, wx[3] * a.w)));
    float rsB = fmaf(wx[4], b.x,
                fmaf(wx[5], b.y,
                fmaf(wx[6], b.z, wx[7] * b.w)));
    return rsA + rsB;
}

template <int NR>  // NR>0: compile-time n_rois (power of 2); NR==0: runtime
__global__ __launch_bounds__(256) void prroi_pool_kernel(
    const float* __restrict__ feat, const float* __restrict__ rois,
    float* __restrict__ out, int n_rois) {
    // Bijective XCD swizzle (nwg = 1792 = 8*224) + c-major decode: XCD k
    // touches only channels [8k, 8k+8) -> per-XCD working set L2-resident.
    int nwg = gridDim.x;
    int cpx = nwg / N_XCD;
    int chunk = (blockIdx.x % N_XCD) * cpx + blockIdx.x / N_XCD;
    int t = chunk * 256 + threadIdx.x;
    int total = n_rois * CH * 4 * OUT_W;
    if (t >= total) return;

    // item = ((c*n_rois + n)*4 + k)*7 + q ; thread covers p0=2k (and p1=2k+1)
    int q = t % OUT_W;
    int rest = t / OUT_W;
    int k = rest & 3;
    rest >>= 2;
    int n, c;
    if constexpr (NR > 0) {
        n = rest & (NR - 1);
        c = rest >> (__builtin_ctz(NR));
    } else {
        n = rest % n_rois;
        c = rest / n_rois;
    }
    int p0 = 2 * k;
    int dp = (k < 3) ? 1 : 0;  // k=3 -> single bin p=6

    const float* r = rois + n * 5;
    int b = (int)r[0];
    float x1 = r[1] * SPATIAL_SCALE;
    float y1 = r[2] * SPATIAL_SCALE;
    float x2 = r[3] * SPATIAL_SCALE;
    float y2 = r[4] * SPATIAL_SCALE;
    float bw = fmaxf(x2 - x1, 0.0f) * (1.0f / OUT_W);
    float bh = fmaxf(y2 - y1, 0.0f) * (1.0f / OUT_H);

    float u0x = x1 + (float)q * bw, u1x = u0x + bw;
    float u0yA = y1 + (float)p0 * bh;             // bin A = [u0yA, u0yA+bh]
    float u1yB = y1 + (float)(p0 + dp + 1) * bh;  // bottom of bin B

    int ws = min(max((int)ceilf(u0x - 1.0f), 0), FW - SUPX);
    int hs = max((int)ceilf(u0yA - 1.0f), 0);
    int he = min((int)floorf(u1yB + 1.0f), FH - 1);
    int hcount = he - hs + 1;
    if (hcount < 1) hcount = 1;

    const float* base = feat + (((size_t)b * CH + c) * FH) * FW + ws;

    // Row-0 loads issued before the wx computation (latency hides under it).
    const float* row0 = base + hs * FW;
    f4u va = *reinterpret_cast<const f4u*>(row0);
    f4u vb = *reinterpret_cast<const f4u*>(row0 + 4);

    float wx[SUPX];
    float dx0 = u0x - (float)ws, dx1 = u1x - (float)ws;
#pragma unroll
    for (int j = 0; j < SUPX; ++j) {
        wx[j] = hat_cdf_c(dx1) - hat_cdf_c(dx0);
        dx0 -= 1.0f; dx1 -= 1.0f;
    }

    // Shared-mid y weights: bins adjacent (u1A == u0B when dp=1), so per row
    // only 3 cdf evals: wyA = C(dm)-C(d0), wyB = C(d1)-C(dm).
    // dp=0: d1==dm -> wyB==0, and the second store is skipped anyway.
    float d0 = u0yA - (float)hs;
    float dm = d0 + bh;
    float d1 = dm + (float)dp * bh;
    float accA = 0.0f, accB = 0.0f;

    for (int i = 0; i < hcount - 1; ++i) {
        const float* rn = base + (hs + i + 1) * FW;
        f4u na = *reinterpret_cast<const f4u*>(rn);
        f4u nb = *reinterpret_cast<const f4u*>(rn + 4);
        float c0 = hat_cdf_c(d0), cmv = hat_cdf_c(dm), c1v = hat_cdf_c(d1);
        float wyA = cmv - c0, wyB = c1v - cmv;
        d0 -= 1.0f; dm -= 1.0f; d1 -= 1.0f;
        float rs = row_dot(wx, va, vb);
        accA = fmaf(wyA, rs, accA);
        accB = fmaf(wyB, rs, accB);
        va = na; vb = nb;
    }
    // last row (no prefetch)
    {
        float c0 = hat_cdf_c(d0), cmv = hat_cdf_c(dm), c1v = hat_cdf_c(d1);
        float wyA = cmv - c0, wyB = c1v - cmv;
        float rs = row_dot(wx, va, vb);
        accA = fmaf(wyA, rs, accA);
        accB = fmaf(wyB, rs, accB);
    }

    float area = bw * bh;
    float inv = 1.0f / fmaxf(area, 1e-12f);
    bool ok = area > 0.0f;
    size_t obase = ((size_t)n * CH + c) * (OUT_H * OUT_W) + q;
    out[obase + (size_t)p0 * OUT_W] = ok ? accA * inv : 0.0f;
    if (dp) out[obase + (size_t)(p0 + 1) * OUT_W] = ok ? accB * inv : 0.0f;
}

extern "C" void kernel_launch(void* const* d_in, const int* in_sizes, int n_in,
                              void* d_out, int out_size, void* d_ws, size_t ws_size,
                              hipStream_t stream) {
    const float* feat = (const float*)d_in[0];
    const float* rois = (const float*)d_in[1];
    float* out = (float*)d_out;
    int n_rois = in_sizes[1] / 5;
    int total = n_rois * CH * 4 * OUT_W;      // 458752
    int blocks = (total + 255) / 256;         // 1792 = 8 * 224
    if (n_rois == 256) {
        hipLaunchKernelGGL((prroi_pool_kernel<256>), dim3(blocks), dim3(256),
                           0, stream, feat, rois, out, n_rois);
    } else {
        hipLaunchKernelGGL((prroi_pool_kernel<0>), dim3(blocks), dim3(256),
                           0, stream, feat, rois, out, n_rois);
    }
}